// Round 4
// baseline (82.136 us; speedup 1.0000x reference)
//
#include <hip/hip_runtime.h>
#include <math.h>

#define S_IMG 160
#define NPIX (S_IMG * S_IMG)      // 25600
#define NF 4096
#define NTILE 100                 // 10 x 10 tiles of 16x16 pixels
#define MAXCH 64
#define INV_LN2 1.4426950408889634f
#define CULL_THRESH -25.0f        // 2^d < 2^-25 => fma(P,e,P) == P bitwise

// ---- projection constants (hardcoded from reference) ----
#define ROT_EPS 6.123234e-17f
#define CAM_Z 2.732f
#define VIEW_TAN 0.5773502691896258f

#if __has_builtin(__builtin_amdgcn_exp2f)
#define EXP2F(x) __builtin_amdgcn_exp2f(x)
#else
#define EXP2F(x) exp2f(x)
#endif

__device__ __forceinline__ float2 project_vert(const float* __restrict__ v, int i) {
    float x = v[3 * i], y = v[3 * i + 1], z = v[3 * i + 2];
    float vx = fmaf(ROT_EPS, x, z);
    float vy = y;
    float vz = fmaf(ROT_EPS, z, -x) + CAM_Z;
    float denom = vz * VIEW_TAN;
    return make_float2((vx / denom + 1.0f) * (S_IMG * 0.5f),
                       (vy / denom + 1.0f) * (S_IMG * 0.5f));
}

// K1: one block per tile. Fused face setup + rect cull + ordered compaction of
// COEFFICIENTS into the per-tile list, padded to a multiple of 64 with dummy
// faces (e = 0). Also zeroes the tickets used by K2 (fresh every call).
__global__ void __launch_bounds__(256) setup_cull(const float* __restrict__ verts,
                                                  const int* __restrict__ faces,
                                                  float* __restrict__ list,
                                                  int* __restrict__ counts,
                                                  unsigned* __restrict__ tickets,
                                                  unsigned* __restrict__ gticket) {
    const int t = blockIdx.x;
    const int tid = threadIdx.x;
    if (tid == 0) tickets[t] = 0u;
    if (t == 0 && tid == 32) *gticket = 0u;

    const int wid = tid >> 6;
    const int lane = tid & 63;
    const float cx = (float)((t % 10) * 16) + 8.0f;
    const float cy = (float)((t / 10) * 16) + 8.0f;

    __shared__ int wcnt[4];
    __shared__ int sbase;
    if (tid == 0) sbase = 0;

    float* mylist = list + (size_t)t * (NF * 12);

    for (int r = 0; r < NF / 256; ++r) {
        int f = r * 256 + tid;
        int i0 = faces[3 * f], i1 = faces[3 * f + 1], i2 = faces[3 * f + 2];
        float2 a = project_vert(verts, i0);
        float2 b = project_vert(verts, i1);
        float2 c = project_vert(verts, i2);
        float area = (b.x - a.x) * (c.y - a.y) - (b.y - a.y) * (c.x - a.x);
        float sg = (area >= 0.0f) ? 1.0f : -1.0f;
        bool valid = fabsf(area) > 1e-6f;

        float o[9];
        float umin = 1e30f;
        float2 p0s[3] = {a, b, c};
        float2 p1s[3] = {b, c, a};
#pragma unroll
        for (int e = 0; e < 3; ++e) {
            float dx = p1s[e].x - p0s[e].x;
            float dy = p1s[e].y - p0s[e].y;
            float L = sqrtf(dx * dx + dy * dy) + 1e-8f;
            float s = sg * INV_LN2 / L;
            float A = valid ? (-dy * s) : 0.0f;
            float B = valid ? (dx * s) : 0.0f;
            float C = valid ? ((dy * p0s[e].x - dx * p0s[e].y) * s) : -1e30f;
            o[3 * e + 0] = A;
            o[3 * e + 1] = B;
            o[3 * e + 2] = C;
            float Cadj = valid ? fmaf(fabsf(A) + fabsf(B), 7.5f, C) : -1e30f;
            umin = fminf(umin, fmaf(A, cx, fmaf(B, cy, Cadj)));
        }
        bool pred = umin >= CULL_THRESH;
        unsigned long long m = __ballot(pred);
        if (lane == 0) wcnt[wid] = __popcll(m);
        __syncthreads();
        int off = sbase;
#pragma unroll
        for (int w = 0; w < 3; ++w)
            if (w < wid) off += wcnt[w];
        off += __popcll(m & ((1ull << lane) - 1ull));
        if (pred) {
            float4* dst = (float4*)(mylist + (size_t)off * 12);
            dst[0] = make_float4(o[0], o[1], o[2], o[3]);
            dst[1] = make_float4(o[4], o[5], o[6], o[7]);
            dst[2] = make_float4(o[8], 0.0f, 0.0f, 0.0f);
        }
        __syncthreads();
        if (tid == 0) sbase += wcnt[0] + wcnt[1] + wcnt[2] + wcnt[3];
    }
    __syncthreads();
    int cnt = sbase;
    int nk = max(1, (cnt + 63) >> 6);
    int pad = nk * 64 - cnt;
    for (int i = tid; i < pad; i += 256) {
        float4* dst = (float4*)(mylist + (size_t)(cnt + i) * 12);
        dst[0] = make_float4(0.0f, 0.0f, -1e30f, 0.0f);
        dst[1] = make_float4(0.0f, -1e30f, 0.0f, 0.0f);
        dst[2] = make_float4(-1e30f, 0.0f, 0.0f, 0.0f);
    }
    if (tid == 0) counts[t] = cnt;
}

// K2: grid (NTILE, MAXCH), 1 wave per block. Chunk (t,k) evaluates 64
// survivors (padded) for its 16x16 tile, writes its partial layer. The LAST
// chunk-block of a tile (per-tile ticket) finishes the tile: multiplies layers
// in fixed k order, writes image + tile SSE. The last tile (global ticket)
// reduces bsums in fixed order -> loss. All arithmetic fixed-order.
__global__ void __launch_bounds__(64) cover_finish(const float* __restrict__ list,
                                                   const int* __restrict__ counts,
                                                   unsigned* __restrict__ tickets,
                                                   unsigned* __restrict__ gticket,
                                                   const float* __restrict__ img_ref,
                                                   float* __restrict__ partials,
                                                   float* __restrict__ bsums,
                                                   float* __restrict__ out) {
    const int t = blockIdx.x;
    const int k = blockIdx.y;
    const int cnt = counts[t];
    const int nk = max(1, (cnt + 63) >> 6);
    if (k >= nk) return;

    __shared__ float4 lds[64 * 3];
    __shared__ int slast;
    const int lane = threadIdx.x;
    {
        const float4* src = (const float4*)(list + ((size_t)t * NF + (size_t)k * 64 + lane) * 12);
        lds[lane * 3 + 0] = src[0];
        lds[lane * 3 + 1] = src[1];
        lds[lane * 3 + 2] = src[2];
    }
    __syncthreads();

    const int colL = lane & 15;
    const int rowL = (lane >> 4) * 4;
    const int col = (t % 10) * 16 + colL;
    const int row0 = (t / 10) * 16 + rowL;
    const float px = (float)col + 0.5f;
    const float py0 = (float)row0 + 0.5f;
    const float py1 = py0 + 1.0f, py2 = py0 + 2.0f, py3 = py0 + 3.0f;

    float P0 = 1.0f, P1 = 1.0f, P2 = 1.0f, P3 = 1.0f;
    for (int j = 0; j < 64; ++j) {
        float4 c0 = lds[3 * j];
        float4 c1 = lds[3 * j + 1];
        float4 c2 = lds[3 * j + 2];
        float b1 = fmaf(c0.x, px, c0.z);
        float b2 = fmaf(c0.w, px, c1.y);
        float b3 = fmaf(c1.z, px, c2.x);
        {
            float d1 = fmaf(c0.y, py0, b1), d2 = fmaf(c1.x, py0, b2), d3 = fmaf(c1.w, py0, b3);
            float e = EXP2F(fminf(fminf(d1, d2), d3));
            P0 = fmaf(P0, e, P0);
        }
        {
            float d1 = fmaf(c0.y, py1, b1), d2 = fmaf(c1.x, py1, b2), d3 = fmaf(c1.w, py1, b3);
            float e = EXP2F(fminf(fminf(d1, d2), d3));
            P1 = fmaf(P1, e, P1);
        }
        {
            float d1 = fmaf(c0.y, py2, b1), d2 = fmaf(c1.x, py2, b2), d3 = fmaf(c1.w, py2, b3);
            float e = EXP2F(fminf(fminf(d1, d2), d3));
            P2 = fmaf(P2, e, P2);
        }
        {
            float d1 = fmaf(c0.y, py3, b1), d2 = fmaf(c1.x, py3, b2), d3 = fmaf(c1.w, py3, b3);
            float e = EXP2F(fminf(fminf(d1, d2), d3));
            P3 = fmaf(P3, e, P3);
        }
    }

    size_t base = ((size_t)t * MAXCH + k) * 256 + (size_t)rowL * 16 + colL;
    partials[base] = __builtin_amdgcn_rcpf(P0);
    partials[base + 16] = __builtin_amdgcn_rcpf(P1);
    partials[base + 32] = __builtin_amdgcn_rcpf(P2);
    partials[base + 48] = __builtin_amdgcn_rcpf(P3);

    // ---- per-tile ticket: last chunk-block finishes the tile ----
    __threadfence();  // release: partials visible device-wide
    if (lane == 0) slast = (atomicAdd(&tickets[t], 1u) == (unsigned)(nk - 1)) ? 1 : 0;
    __syncthreads();
    if (!slast) return;
    __threadfence();  // acquire: see other blocks' partials

    float pr0 = 1.0f, pr1 = 1.0f, pr2 = 1.0f, pr3 = 1.0f;
    for (int kk = 0; kk < nk; ++kk) {
        size_t b = ((size_t)t * MAXCH + kk) * 256 + (size_t)rowL * 16 + colL;
        pr0 *= partials[b];
        pr1 *= partials[b + 16];
        pr2 *= partials[b + 32];
        pr3 *= partials[b + 48];
    }
    int p = row0 * S_IMG + col;
    float i0 = 1.0f - pr0, i1 = 1.0f - pr1, i2 = 1.0f - pr2, i3 = 1.0f - pr3;
    out[p] = i0;
    out[p + S_IMG] = i1;
    out[p + 2 * S_IMG] = i2;
    out[p + 3 * S_IMG] = i3;
    float d0 = i0 - img_ref[p];
    float d1 = i1 - img_ref[p + S_IMG];
    float d2 = i2 - img_ref[p + 2 * S_IMG];
    float d3 = i3 - img_ref[p + 3 * S_IMG];
    float sse = d0 * d0;
    sse += d1 * d1;
    sse += d2 * d2;
    sse += d3 * d3;
#pragma unroll
    for (int off = 32; off > 0; off >>= 1) sse += __shfl_down(sse, off);
    if (lane == 0) bsums[t] = sse;

    // ---- global ticket: last tile reduces the loss ----
    __threadfence();
    if (lane == 0) slast = (atomicAdd(gticket, 1u) == (unsigned)(NTILE - 1)) ? 1 : 0;
    __syncthreads();
    if (!slast) return;
    __threadfence();

    float v = 0.0f;
    if (lane < 50) v = bsums[lane] + bsums[lane + 50];
#pragma unroll
    for (int off = 32; off > 0; off >>= 1) v += __shfl_down(v, off);
    if (lane == 0) out[NPIX] = v;
}

extern "C" void kernel_launch(void* const* d_in, const int* in_sizes, int n_in,
                              void* d_out, int out_size, void* d_ws, size_t ws_size,
                              hipStream_t stream) {
    const float* verts = (const float*)d_in[0];
    const int* faces = (const int*)d_in[1];
    const float* img_ref = (const float*)d_in[2];
    float* out = (float*)d_out;

    // workspace layout (16B aligned)
    float* list = (float*)d_ws;                                 // NTILE*NF*12 f = 19.66 MB
    float* partials = list + (size_t)NTILE * NF * 12;           // NTILE*MAXCH*256 f = 6.55 MB
    int* counts = (int*)(partials + (size_t)NTILE * MAXCH * 256);  // 100 (+pad)
    unsigned* tickets = (unsigned*)(counts + 128);              // 100 (+pad)
    unsigned* gticket = tickets + 128;                          // 1 (+pad)
    float* bsums = (float*)(gticket + 128);                     // 100

    setup_cull<<<NTILE, 256, 0, stream>>>(verts, faces, list, counts, tickets, gticket);
    cover_finish<<<dim3(NTILE, MAXCH), 64, 0, stream>>>(list, counts, tickets, gticket,
                                                        img_ref, partials, bsums, out);
}

// Round 5
// 55.060 us; speedup vs baseline: 1.4917x; 1.4917x over previous
//
#include <hip/hip_runtime.h>
#include <math.h>

#define S_IMG 160
#define NPIX (S_IMG * S_IMG)   // 25600
#define NF 4096
#define TS 8                   // tile size 8x8
#define NTX 20                 // tiles per row
#define NTILE 400
#define CH 16                  // faces per chunk/item
#define CAP NF                 // per-tile list capacity (faces)
#define MAXK 256               // max chunks per tile
#define NBLK2 1024             // cover blocks
#define NWAVE2 (NBLK2 * 4)     // cover waves
#define INV_LN2 1.4426950408889634f
#define CULL_THRESH -25.0f     // 2^d < 2^-25 => fma(P,e,P) == P bitwise

#define ROT_EPS 6.123234e-17f
#define CAM_Z 2.732f
#define VIEW_TAN 0.5773502691896258f

#if __has_builtin(__builtin_amdgcn_exp2f)
#define EXP2F(x) __builtin_amdgcn_exp2f(x)
#else
#define EXP2F(x) exp2f(x)
#endif

__device__ __forceinline__ float2 project_vert(const float* __restrict__ v, int i) {
    float x = v[3 * i], y = v[3 * i + 1], z = v[3 * i + 2];
    float vx = fmaf(ROT_EPS, x, z);
    float vy = y;
    float vz = fmaf(ROT_EPS, z, -x) + CAM_Z;
    float denom = vz * VIEW_TAN;
    return make_float2((vx / denom + 1.0f) * (S_IMG * 0.5f),
                       (vy / denom + 1.0f) * (S_IMG * 0.5f));
}

// K1: one block per 8x8 tile. Fused setup + rect-cull + ordered compaction of
// coefficients into 16-face chunks; appends (t,k) items to a global list.
__global__ void __launch_bounds__(512) setup_cull(const float* __restrict__ verts,
                                                  const int* __restrict__ faces,
                                                  float* __restrict__ list,
                                                  int* __restrict__ nk_arr,
                                                  int* __restrict__ items,
                                                  unsigned* __restrict__ nitems) {
    const int t = blockIdx.x;
    const int tid = threadIdx.x;
    const int wid = tid >> 6;
    const int lane = tid & 63;
    const float cx = (float)((t % NTX) * TS) + 4.0f;   // pixel centers span +-3.5
    const float cy = (float)((t / NTX) * TS) + 4.0f;

    __shared__ int wcnt[8];
    __shared__ unsigned sitem;

    float* mylist = list + (size_t)t * CAP * 12;
    int base = 0;

    for (int r = 0; r < NF / 512; ++r) {
        int f = r * 512 + tid;
        int i0 = faces[3 * f], i1 = faces[3 * f + 1], i2 = faces[3 * f + 2];
        float2 a = project_vert(verts, i0);
        float2 b = project_vert(verts, i1);
        float2 c = project_vert(verts, i2);
        float area = (b.x - a.x) * (c.y - a.y) - (b.y - a.y) * (c.x - a.x);
        float sg = (area >= 0.0f) ? 1.0f : -1.0f;
        bool valid = fabsf(area) > 1e-6f;

        float o[9];
        float umin = 1e30f;
        float2 p0s[3] = {a, b, c};
        float2 p1s[3] = {b, c, a};
#pragma unroll
        for (int e = 0; e < 3; ++e) {
            float dx = p1s[e].x - p0s[e].x;
            float dy = p1s[e].y - p0s[e].y;
            float L = sqrtf(dx * dx + dy * dy) + 1e-8f;
            float s = sg * INV_LN2 / L;
            float A = valid ? (-dy * s) : 0.0f;
            float B = valid ? (dx * s) : 0.0f;
            float C = valid ? ((dy * p0s[e].x - dx * p0s[e].y) * s) : -1e30f;
            o[3 * e + 0] = A;
            o[3 * e + 1] = B;
            o[3 * e + 2] = C;
            float Cadj = valid ? fmaf(fabsf(A) + fabsf(B), 3.5f, C) : -1e30f;
            umin = fminf(umin, fmaf(A, cx, fmaf(B, cy, Cadj)));
        }
        bool pred = umin >= CULL_THRESH;
        unsigned long long m = __ballot(pred);
        int wpop = __popcll(m);
        int prefix = __popcll(m & ((1ull << lane) - 1ull));

        __syncthreads();                 // protect wcnt vs previous round's reads
        if (lane == 0) wcnt[wid] = wpop;
        __syncthreads();
        int off = base;
#pragma unroll
        for (int w = 0; w < 8; ++w) {
            int cw = wcnt[w];
            if (w < wid) off += cw;
            base += cw;                  // every thread tracks the running total
        }
        off += prefix;
        if (pred) {
            float4* dst = (float4*)(mylist + (size_t)off * 12);
            dst[0] = make_float4(o[0], o[1], o[2], o[3]);
            dst[1] = make_float4(o[4], o[5], o[6], o[7]);
            dst[2] = make_float4(o[8], 0.0f, 0.0f, 0.0f);
        }
    }
    __syncthreads();

    int cnt = base;
    int nkt = max(1, (cnt + CH - 1) >> 4);
    int padcnt = nkt * CH - cnt;
    for (int i = tid; i < padcnt; i += 512) {     // dummy faces: e = 2^-inf = 0
        float4* dst = (float4*)(mylist + (size_t)(cnt + i) * 12);
        dst[0] = make_float4(0.0f, 0.0f, -1e30f, 0.0f);
        dst[1] = make_float4(0.0f, -1e30f, 0.0f, 0.0f);
        dst[2] = make_float4(-1e30f, 0.0f, 0.0f, 0.0f);
    }
    if (tid == 0) {
        nk_arr[t] = nkt;
        sitem = atomicAdd(nitems, (unsigned)nkt);
    }
    __syncthreads();
    unsigned ibase = sitem;
    for (int i = tid; i < nkt; i += 512) items[ibase + i] = (t << 8) | i;
}

// K2: fixed grid, 4096 waves, static strided item assignment (no atomics, no
// barriers - waves are independent). Wave-private LDS staging of the item's
// 16 faces (48-lane coalesced burst), then 16-face product for 64 pixels.
__global__ void __launch_bounds__(256) cover(const float* __restrict__ list,
                                             const int* __restrict__ items,
                                             const unsigned* __restrict__ nitems,
                                             float* __restrict__ partials) {
    __shared__ float slds[4][CH * 12];
    const int wid = threadIdx.x >> 6;
    const int lane = threadIdx.x & 63;
    const int gw = blockIdx.x * 4 + wid;
    const int NIT = (int)*nitems;
    float* myl = slds[wid];

    for (int it = gw; it < NIT; it += NWAVE2) {
        int item = items[it];
        int t = item >> 8, k = item & 255;
        const float4* src = (const float4*)(list + ((size_t)t * CAP + (size_t)k * CH) * 12);
        if (lane < CH * 3) ((float4*)myl)[lane] = src[lane];
        asm volatile("s_waitcnt lgkmcnt(0)" ::: "memory");  // ds_write data landed

        float px = (float)((t % NTX) * TS + (lane & 7)) + 0.5f;
        float py = (float)((t / NTX) * TS + (lane >> 3)) + 0.5f;
        float P = 1.0f;
#pragma unroll 4
        for (int j = 0; j < CH; ++j) {
            float4 c0 = ((float4*)myl)[3 * j];
            float4 c1 = ((float4*)myl)[3 * j + 1];
            float4 c2 = ((float4*)myl)[3 * j + 2];
            float d1 = fmaf(c0.x, px, fmaf(c0.y, py, c0.z));
            float d2 = fmaf(c0.w, px, fmaf(c1.x, py, c1.y));
            float d3 = fmaf(c1.z, px, fmaf(c1.w, py, c2.x));
            float e = EXP2F(fminf(fminf(d1, d2), d3));
            P = fmaf(P, e, P);
        }
        partials[((size_t)t * MAXK + k) * 64 + lane] = __builtin_amdgcn_rcpf(P);
    }
}

// K3: wave = tile (4 tiles per block). Fixed-k-order product, image + tile SSE.
__global__ void __launch_bounds__(256) finish(const float* __restrict__ partials,
                                              const int* __restrict__ nk_arr,
                                              const float* __restrict__ img_ref,
                                              float* __restrict__ out,
                                              float* __restrict__ bsums) {
    const int wid = threadIdx.x >> 6;
    const int lane = threadIdx.x & 63;
    const int t = blockIdx.x * 4 + wid;
    const int nkt = nk_arr[t];
    float prod = 1.0f;
    const float* pp = partials + (size_t)t * MAXK * 64 + lane;
#pragma unroll 4
    for (int k = 0; k < nkt; ++k) prod *= pp[(size_t)k * 64];
    float img = 1.0f - prod;
    int col = (t % NTX) * TS + (lane & 7);
    int row = (t / NTX) * TS + (lane >> 3);
    int p = row * S_IMG + col;
    out[p] = img;
    float d = img - img_ref[p];
    float sse = d * d;
#pragma unroll
    for (int off = 32; off > 0; off >>= 1) sse += __shfl_down(sse, off);
    if (lane == 0) bsums[t] = sse;
}

// K4: fixed-order global reduction of 400 tile SSEs.
__global__ void __launch_bounds__(64) loss_kernel(const float* __restrict__ bsums,
                                                  float* __restrict__ loss_out) {
    int lane = threadIdx.x;
    float v = 0.0f;
    for (int i = lane; i < NTILE; i += 64) v += bsums[i];
#pragma unroll
    for (int off = 32; off > 0; off >>= 1) v += __shfl_down(v, off);
    if (lane == 0) loss_out[0] = v;
}

extern "C" void kernel_launch(void* const* d_in, const int* in_sizes, int n_in,
                              void* d_out, int out_size, void* d_ws, size_t ws_size,
                              hipStream_t stream) {
    const float* verts = (const float*)d_in[0];
    const int* faces = (const int*)d_in[1];
    const float* img_ref = (const float*)d_in[2];
    float* out = (float*)d_out;

    // workspace layout (16B aligned throughout)
    float* list = (float*)d_ws;                               // 400*4096*12 f = 78.6 MB
    float* partials = list + (size_t)NTILE * CAP * 12;        // 400*256*64 f  = 26.2 MB
    int* items = (int*)(partials + (size_t)NTILE * MAXK * 64);  // 400*256 ints
    int* nk_arr = items + (size_t)NTILE * MAXK;               // 400 ints
    float* bsums = (float*)(nk_arr + 512);                    // 400 floats
    unsigned* nitems = (unsigned*)(bsums + 512);              // 1 (+pad)

    hipMemsetAsync(nitems, 0, sizeof(unsigned), stream);
    setup_cull<<<NTILE, 512, 0, stream>>>(verts, faces, list, nk_arr, items, nitems);
    cover<<<NBLK2, 256, 0, stream>>>(list, items, nitems, partials);
    finish<<<NTILE / 4, 256, 0, stream>>>(partials, nk_arr, img_ref, out, bsums);
    loss_kernel<<<1, 64, 0, stream>>>(bsums, out + NPIX);
}

// Round 6
// 38.047 us; speedup vs baseline: 2.1588x; 1.4472x over previous
//
#include <hip/hip_runtime.h>
#include <math.h>

#define S_IMG 160
#define NPIX (S_IMG * S_IMG)   // 25600
#define NF 4096
#define TS 16                  // tile size 16x16
#define NTX 10                 // tiles per row
#define NTILE 100
#define CAP NF                 // per-tile survivor capacity (faces)
#define MAXK 64                // max 64-face chunks per tile
#define INV_LN2 1.4426950408889634f
#define CULL_THRESH -25.0f     // 2^d < 2^-25 => fma(P,e,P) == P bitwise

#define ROT_EPS 6.123234e-17f
#define CAM_Z 2.732f
#define VIEW_TAN 0.5773502691896258f

#if __has_builtin(__builtin_amdgcn_exp2f)
#define EXP2F(x) __builtin_amdgcn_exp2f(x)
#else
#define EXP2F(x) exp2f(x)
#endif

__device__ __forceinline__ float2 project_vert(const float* __restrict__ v, int i) {
    float x = v[3 * i], y = v[3 * i + 1], z = v[3 * i + 2];
    float vx = fmaf(ROT_EPS, x, z);
    float vy = y;
    float vz = fmaf(ROT_EPS, z, -x) + CAM_Z;
    float denom = vz * VIEW_TAN;
    return make_float2((vx / denom + 1.0f) * (S_IMG * 0.5f),
                       (vy / denom + 1.0f) * (S_IMG * 0.5f));
}

// K1: one block per 16x16 tile. Fused setup + rect-cull + ordered ballot
// compaction of coefficients, padded to a multiple of 64 with dummy faces
// (C=-1e30 -> e=0 -> no-op). No atomics, no cross-call state.
__global__ void __launch_bounds__(512) setup_cull(const float* __restrict__ verts,
                                                  const int* __restrict__ faces,
                                                  float* __restrict__ list,
                                                  int* __restrict__ nk_arr) {
    const int t = blockIdx.x;
    const int tid = threadIdx.x;
    const int wid = tid >> 6;
    const int lane = tid & 63;
    const float cx = (float)((t % NTX) * TS) + 8.0f;   // centers span +-7.5
    const float cy = (float)((t / NTX) * TS) + 8.0f;

    __shared__ int wcnt[8];
    float* mylist = list + (size_t)t * CAP * 12;
    int base = 0;

    for (int r = 0; r < NF / 512; ++r) {
        int f = r * 512 + tid;
        int i0 = faces[3 * f], i1 = faces[3 * f + 1], i2 = faces[3 * f + 2];
        float2 a = project_vert(verts, i0);
        float2 b = project_vert(verts, i1);
        float2 c = project_vert(verts, i2);
        float area = (b.x - a.x) * (c.y - a.y) - (b.y - a.y) * (c.x - a.x);
        float sg = (area >= 0.0f) ? 1.0f : -1.0f;
        bool valid = fabsf(area) > 1e-6f;

        float o[9];
        float umin = 1e30f;
        float2 p0s[3] = {a, b, c};
        float2 p1s[3] = {b, c, a};
#pragma unroll
        for (int e = 0; e < 3; ++e) {
            float dx = p1s[e].x - p0s[e].x;
            float dy = p1s[e].y - p0s[e].y;
            float L = sqrtf(dx * dx + dy * dy) + 1e-8f;
            float s = sg * INV_LN2 / L;
            float A = valid ? (-dy * s) : 0.0f;
            float B = valid ? (dx * s) : 0.0f;
            float C = valid ? ((dy * p0s[e].x - dx * p0s[e].y) * s) : -1e30f;
            o[3 * e + 0] = A;
            o[3 * e + 1] = B;
            o[3 * e + 2] = C;
            float Cadj = valid ? fmaf(fabsf(A) + fabsf(B), 7.5f, C) : -1e30f;
            umin = fminf(umin, fmaf(A, cx, fmaf(B, cy, Cadj)));
        }
        bool pred = umin >= CULL_THRESH;
        unsigned long long m = __ballot(pred);
        int wpop = __popcll(m);
        int prefix = __popcll(m & ((1ull << lane) - 1ull));

        __syncthreads();                 // protect wcnt vs previous round
        if (lane == 0) wcnt[wid] = wpop;
        __syncthreads();
        int off = base;
#pragma unroll
        for (int w = 0; w < 8; ++w) {
            int cw = wcnt[w];
            if (w < wid) off += cw;
            base += cw;                  // running total, same in every thread
        }
        off += prefix;
        if (pred) {
            float4* dst = (float4*)(mylist + (size_t)off * 12);
            dst[0] = make_float4(o[0], o[1], o[2], o[3]);
            dst[1] = make_float4(o[4], o[5], o[6], o[7]);
            dst[2] = make_float4(o[8], 0.0f, 0.0f, 0.0f);
        }
    }
    __syncthreads();

    int cnt = base;
    int nkt = (cnt + 63) >> 6;           // 0 allowed: tile fully empty
    int padcnt = nkt * 64 - cnt;
    for (int i = tid; i < padcnt; i += 512) {
        float4* dst = (float4*)(mylist + (size_t)(cnt + i) * 12);
        dst[0] = make_float4(0.0f, 0.0f, -1e30f, 0.0f);
        dst[1] = make_float4(0.0f, -1e30f, 0.0f, 0.0f);
        dst[2] = make_float4(-1e30f, 0.0f, 0.0f, 0.0f);
    }
    if (tid == 0) nk_arr[t] = nkt;
}

// K2: grid (NTILE, MAXK), 1 wave per block, early exit when k >= nk[t].
// 16x16 pixel tile, 4 rows/thread; per-wave LDS stage of the 64-face chunk.
__global__ void __launch_bounds__(64) cover(const float* __restrict__ list,
                                            const int* __restrict__ nk_arr,
                                            float* __restrict__ partials) {
    const int t = blockIdx.x;
    const int k = blockIdx.y;
    if (k >= nk_arr[t]) return;

    __shared__ float4 lds[64 * 3];
    const int lane = threadIdx.x;
    {
        const float4* src = (const float4*)(list + ((size_t)t * CAP + (size_t)k * 64) * 12);
#pragma unroll
        for (int i = 0; i < 3; ++i) lds[lane + i * 64] = src[lane + i * 64];
    }
    asm volatile("s_waitcnt lgkmcnt(0)" ::: "memory");  // single wave: data landed

    const int colL = lane & 15;
    const int rowL = (lane >> 4) * 4;
    const float px = (float)((t % NTX) * TS + colL) + 0.5f;
    const float py0 = (float)((t / NTX) * TS + rowL) + 0.5f;
    const float py1 = py0 + 1.0f, py2 = py0 + 2.0f, py3 = py0 + 3.0f;

    float P0 = 1.0f, P1 = 1.0f, P2 = 1.0f, P3 = 1.0f;
    for (int j = 0; j < 64; ++j) {
        float4 c0 = lds[j];              // note: [j], [j+64], [j+128] layout
        float4 c1 = lds[j + 64];
        float4 c2 = lds[j + 128];
        // careful: staged as 3 consecutive float4 PER FACE in source order ->
        // face j's quads are at [3j],[3j+1],[3j+2]; we staged linearly, so
        // read with that layout instead:
        c0 = lds[3 * j];
        c1 = lds[3 * j + 1];
        c2 = lds[3 * j + 2];
        float b1 = fmaf(c0.x, px, c0.z);
        float b2 = fmaf(c0.w, px, c1.y);
        float b3 = fmaf(c1.z, px, c2.x);
        {
            float d1 = fmaf(c0.y, py0, b1), d2 = fmaf(c1.x, py0, b2), d3 = fmaf(c1.w, py0, b3);
            float e = EXP2F(fminf(fminf(d1, d2), d3));
            P0 = fmaf(P0, e, P0);
        }
        {
            float d1 = fmaf(c0.y, py1, b1), d2 = fmaf(c1.x, py1, b2), d3 = fmaf(c1.w, py1, b3);
            float e = EXP2F(fminf(fminf(d1, d2), d3));
            P1 = fmaf(P1, e, P1);
        }
        {
            float d1 = fmaf(c0.y, py2, b1), d2 = fmaf(c1.x, py2, b2), d3 = fmaf(c1.w, py2, b3);
            float e = EXP2F(fminf(fminf(d1, d2), d3));
            P2 = fmaf(P2, e, P2);
        }
        {
            float d1 = fmaf(c0.y, py3, b1), d2 = fmaf(c1.x, py3, b2), d3 = fmaf(c1.w, py3, b3);
            float e = EXP2F(fminf(fminf(d1, d2), d3));
            P3 = fmaf(P3, e, P3);
        }
    }

    size_t base = ((size_t)t * MAXK + k) * 256 + (size_t)rowL * 16 + colL;
    partials[base] = __builtin_amdgcn_rcpf(P0);
    partials[base + 16] = __builtin_amdgcn_rcpf(P1);
    partials[base + 32] = __builtin_amdgcn_rcpf(P2);
    partials[base + 48] = __builtin_amdgcn_rcpf(P3);
}

// K3: one block per tile (256 thr = 256 px). Fixed-k-order product, image,
// tile SSE via deterministic tree.
__global__ void __launch_bounds__(256) finish(const float* __restrict__ partials,
                                              const int* __restrict__ nk_arr,
                                              const float* __restrict__ img_ref,
                                              float* __restrict__ out,
                                              float* __restrict__ bsums) {
    const int t = blockIdx.x;
    const int tid = threadIdx.x;
    const int nkt = nk_arr[t];
    float prod = 1.0f;
    for (int k = 0; k < nkt; ++k) prod *= partials[((size_t)t * MAXK + k) * 256 + tid];
    float img = 1.0f - prod;
    int col = (t % NTX) * TS + (tid & 15);
    int row = (t / NTX) * TS + (tid >> 4);
    int p = row * S_IMG + col;
    out[p] = img;
    float d = img - img_ref[p];
    float sq = d * d;
#pragma unroll
    for (int off = 32; off > 0; off >>= 1) sq += __shfl_down(sq, off);
    __shared__ float red[4];
    int lane = tid & 63;
    int wid = tid >> 6;
    if (lane == 0) red[wid] = sq;
    __syncthreads();
    if (tid == 0) bsums[t] = (red[0] + red[1]) + (red[2] + red[3]);
}

// K4: fixed-order reduction of 100 tile SSEs.
__global__ void __launch_bounds__(64) loss_kernel(const float* __restrict__ bsums,
                                                  float* __restrict__ loss_out) {
    int lane = threadIdx.x;
    float v = 0.0f;
    if (lane < NTILE) v = bsums[lane];
    if (lane + 64 < NTILE) v += bsums[lane + 64];
#pragma unroll
    for (int off = 32; off > 0; off >>= 1) v += __shfl_down(v, off);
    if (lane == 0) loss_out[0] = v;
}

extern "C" void kernel_launch(void* const* d_in, const int* in_sizes, int n_in,
                              void* d_out, int out_size, void* d_ws, size_t ws_size,
                              hipStream_t stream) {
    const float* verts = (const float*)d_in[0];
    const int* faces = (const int*)d_in[1];
    const float* img_ref = (const float*)d_in[2];
    float* out = (float*)d_out;

    // workspace layout (16B aligned)
    float* list = (float*)d_ws;                                // 100*4096*12 f = 19.66 MB
    float* partials = list + (size_t)NTILE * CAP * 12;         // 100*64*256 f = 6.55 MB
    int* nk_arr = (int*)(partials + (size_t)NTILE * MAXK * 256);  // 100 ints (+pad)
    float* bsums = (float*)(nk_arr + 128);                     // 100 floats

    setup_cull<<<NTILE, 512, 0, stream>>>(verts, faces, list, nk_arr);
    cover<<<dim3(NTILE, MAXK), 64, 0, stream>>>(list, nk_arr, partials);
    finish<<<NTILE, 256, 0, stream>>>(partials, nk_arr, img_ref, out, bsums);
    loss_kernel<<<1, 64, 0, stream>>>(bsums, out + NPIX);
}